// Round 3
// baseline (8456.994 us; speedup 1.0000x reference)
//
#include <hip/hip_runtime.h>
#include <stdint.h>

#define SLEN    512
#define IDIM    256
#define HDIM    512
#define NROW    256          // 2 sequences x 128 batch rows
#define KP      776          // Ab LDS row stride in halfs (768 + 8)
#define NSTEP   512
#define FSTRIDE 32           // ints between per-WG flags (128 B)

typedef __attribute__((ext_vector_type(8))) _Float16 half8;
typedef __attribute__((ext_vector_type(4))) float   f32x4;

__device__ __forceinline__ float sigm(float x)   { return 1.0f / (1.0f + __expf(-x)); }
__device__ __forceinline__ float tanh_f(float x) { return 2.0f / (1.0f + __expf(-2.0f * x)) - 1.0f; }

__device__ __forceinline__ half8 cvt8(float4 a, float4 b) {
    half8 v;
    v[0] = (_Float16)a.x; v[1] = (_Float16)a.y; v[2] = (_Float16)a.z; v[3] = (_Float16)a.w;
    v[4] = (_Float16)b.x; v[5] = (_Float16)b.y; v[6] = (_Float16)b.z; v[7] = (_Float16)b.w;
    return v;
}

// Persistent LSTM. 256 WGs = 16 batch groups (16 rows) x 16 column groups (32 H-cols
// = 128 gate cols). W frags live in registers (f16), activations [x_t|h_{t-1}] in a
// 25 KB LDS tile. Sync: per-WG monotonic release-store flags (no RMW contention),
// wave-parallel polling, acquire fence. Transposed GEMM: each lane's 4 acc regs are
// gates (i,f,g,o) of one (row, H-col) -> lane-local cell update.
__global__ __launch_bounds__(256, 1)
void lstm_persistent(const float* __restrict__ x0, const float* __restrict__ x1,
                     const float* __restrict__ wih, const float* __restrict__ whh,
                     const float* __restrict__ bih, const float* __restrict__ bhh,
                     _Float16* __restrict__ hb, int* __restrict__ flg,
                     float* __restrict__ out) {
    __shared__ _Float16 Ab[16 * KP];

    const int tid  = threadIdx.x;
    const int lane = tid & 63;
    const int w    = tid >> 6;       // wave 0..3
    const int quad = lane >> 4;
    const int l16  = lane & 15;
    const int igrp = blockIdx.x & 15;    // batch group (16 rows)
    const int jcg  = blockIdx.x >> 4;    // column group (32 H-cols)
    const int mtb  = w * 2;              // my 2 M-tiles (of 8)

    // ---- W A-frags: global fp32 -> f16 registers, once ----
    // arranged row m (0..15) of tile mt: gate q=m&3, H-col-in-tile ccl=m>>2
    // gc = q*512 + jcg*32 + mt*4 + ccl ; A[m=l16][k=quad*8+j], k-chunk kk*32
    const int q0  = l16 & 3, ccl = l16 >> 2;
    const int gc0 = q0 * HDIM + jcg * 32 + mtb * 4 + ccl;
    const int gc1 = gc0 + 4;
    half8 wf0[24], wf1[24];
#pragma unroll
    for (int kk = 0; kk < 24; ++kk) {
        int k0 = kk * 32 + quad * 8;
        const float* sA = (k0 < IDIM) ? wih + (size_t)gc0 * IDIM + k0
                                      : whh + (size_t)gc0 * HDIM + (k0 - IDIM);
        const float* sB = (k0 < IDIM) ? wih + (size_t)gc1 * IDIM + k0
                                      : whh + (size_t)gc1 * HDIM + (k0 - IDIM);
        wf0[kk] = cvt8(*(const float4*)sA, *(const float4*)(sA + 4));
        wf1[kk] = cvt8(*(const float4*)sB, *(const float4*)(sB + 4));
    }

    // ---- bias: C-frag row m = quad*4 + reg -> reg q = gate q at H-col (mt*4+quad) ----
    float bias0[4], bias1[4];
#pragma unroll
    for (int q = 0; q < 4; ++q) {
        int g0 = q * HDIM + jcg * 32 + mtb * 4 + quad;
        bias0[q] = bih[g0] + bhh[g0];
        bias1[q] = bih[g0 + 4] + bhh[g0 + 4];
    }

    const float* xp  = (igrp < 8) ? x0 : x1;
    const int   brow = (igrp & 7) * 16;
    const int   r0   = tid >> 5;            // my x row (and +8)
    const int   o0   = (tid & 31) * 8;      // my x col chunk
    const int   grow = igrp * 16 + l16;     // my batch row (global)
    const int   cc0  = jcg * 32 + mtb * 4 + quad;  // my H-cols
    const int   cc1  = cc0 + 4;
    const int*  fpoll = flg + (size_t)(igrp * 16 + lane) * FSTRIDE;  // lane<16 polls WG `lane`
    int* fmine = flg + (size_t)(igrp * 16 + jcg) * FSTRIDE;

    float c0 = 0.f, c1 = 0.f;
    int gaveup = 0;   // spin-timeout failsafe

#pragma unroll 1
    for (int t = 0; t < NSTEP; ++t) {
        // ---- prefetch x_t into regs (independent of flags -> overlaps the spin) ----
        const float* xr0 = xp + ((size_t)(brow + r0) * SLEN + t) * IDIM + o0;
        const float* xr1 = xr0 + (size_t)8 * SLEN * IDIM;
        float4 pa = *(const float4*)xr0, pb = *(const float4*)(xr0 + 4);
        float4 pc = *(const float4*)xr1, pd = *(const float4*)(xr1 + 4);

        // ---- wait: all 16 WGs of this group finished step t-1 (flag >= t) ----
        if (t > 0 && !gaveup) {
            if (lane < 16) {
                int it = 0;
                while (__hip_atomic_load(fpoll, __ATOMIC_RELAXED, __HIP_MEMORY_SCOPE_AGENT) < t) {
                    if (++it > (1 << 16)) { gaveup = 1; break; }
                }
            }
            __builtin_amdgcn_fence(__ATOMIC_ACQUIRE, "agent");
        }

        // ---- stage x_t (fp32->f16) and h_{t-1} (f16) into Ab ----
        *(half8*)&Ab[r0 * KP + o0]       = cvt8(pa, pb);
        *(half8*)&Ab[(r0 + 8) * KP + o0] = cvt8(pc, pd);
        const _Float16* hs = hb + (size_t)((t + 1) & 1) * (NROW * HDIM)
                                + (size_t)(igrp * 16) * HDIM;
#pragma unroll
        for (int p = 0; p < 4; ++p) {
            int c = tid + p * 256;
            int row = c >> 6, o8 = (c & 63) * 8;
            *(half8*)&Ab[row * KP + IDIM + o8] = *(const half8*)(hs + (size_t)row * HDIM + o8);
        }
        __syncthreads();

        // ---- GEMM: D[m=gatecol][n=row] += W[m][k] * Act[n][k] ----
        f32x4 acc0 = {bias0[0], bias0[1], bias0[2], bias0[3]};
        f32x4 acc1 = {bias1[0], bias1[1], bias1[2], bias1[3]};
        const _Float16* ab = &Ab[l16 * KP + quad * 8];
#pragma unroll
        for (int kk = 0; kk < 24; ++kk) {
            half8 bf = *(const half8*)(ab + kk * 32);
            acc0 = __builtin_amdgcn_mfma_f32_16x16x32_f16(wf0[kk], bf, acc0, 0, 0, 0);
            acc1 = __builtin_amdgcn_mfma_f32_16x16x32_f16(wf1[kk], bf, acc1, 0, 0, 0);
        }

        // ---- cell update (regs 0..3 = i,f,g,o), fp32 ----
        float i0 = sigm(acc0[0]), f0 = sigm(acc0[1]), g0 = tanh_f(acc0[2]), o0g = sigm(acc0[3]);
        c0 = f0 * c0 + i0 * g0;
        float h0 = o0g * tanh_f(c0);
        float i1 = sigm(acc1[0]), f1 = sigm(acc1[1]), g1 = tanh_f(acc1[2]), o1g = sigm(acc1[3]);
        c1 = f1 * c1 + i1 * g1;
        float h1 = o1g * tanh_f(c1);

        if (t < NSTEP - 1) {
            _Float16* hd = hb + (size_t)(t & 1) * (NROW * HDIM) + (size_t)grow * HDIM;
            hd[cc0] = (_Float16)h0;
            hd[cc1] = (_Float16)h1;
            __syncthreads();   // all waves' h stores + Ab reads done (vmcnt(0) at barrier)
            if (tid == 0)
                __hip_atomic_store(fmine, t + 1, __ATOMIC_RELEASE, __HIP_MEMORY_SCOPE_AGENT);
        } else {
            out[(size_t)grow * HDIM + cc0] = h0;
            out[(size_t)grow * HDIM + cc1] = h1;
        }
    }
}

extern "C" void kernel_launch(void* const* d_in, const int* in_sizes, int n_in,
                              void* d_out, int out_size, void* d_ws, size_t ws_size,
                              hipStream_t stream) {
    const float* x0  = (const float*)d_in[0];   // [128,512,256] fp32
    const float* x1  = (const float*)d_in[1];
    const float* wih = (const float*)d_in[2];   // [2048,256]
    const float* whh = (const float*)d_in[3];   // [2048,512]
    const float* bih = (const float*)d_in[4];   // [2048]
    const float* bhh = (const float*)d_in[5];   // [2048]

    // ws: h ping-pong (2 x 256 KB f16) + 256 per-WG monotonic flags (128 B apart)
    _Float16* hb = (_Float16*)d_ws;
    int* flg = (int*)((char*)d_ws + (size_t)2 * NROW * HDIM * sizeof(_Float16));
    size_t zbytes = (size_t)2 * NROW * HDIM * sizeof(_Float16)
                  + (size_t)256 * FSTRIDE * sizeof(int);
    hipMemsetAsync(d_ws, 0, zbytes, stream);   // zero h_{-1} + flags (ws is 0xAA-poisoned)

    lstm_persistent<<<dim3(256), dim3(256), 0, stream>>>(
        x0, x1, wih, whh, bih, bhh, hb, flg, (float*)d_out);
}

// Round 4
// 2561.786 us; speedup vs baseline: 3.3012x; 3.3012x over previous
//
#include <hip/hip_runtime.h>
#include <stdint.h>

#define SLEN    512
#define IDIM    256
#define HDIM    512
#define NROW    256          // 2 sequences x 128 batch rows
#define KP      776          // Ab LDS row stride in halfs (768 + 8)
#define NSTEP   512
#define NGRP    16           // batch groups (16 rows each)
#define GWG     16           // WGs (column groups) per batch group

typedef __attribute__((ext_vector_type(8))) _Float16 half8;
typedef __attribute__((ext_vector_type(4))) float   f32x4;

__device__ __forceinline__ float sigm(float x)   { return 1.0f / (1.0f + __expf(-x)); }
__device__ __forceinline__ float tanh_f(float x) { return 2.0f / (1.0f + __expf(-2.0f * x)) - 1.0f; }

__device__ __forceinline__ half8 cvt8(float4 a, float4 b) {
    half8 v;
    v[0] = (_Float16)a.x; v[1] = (_Float16)a.y; v[2] = (_Float16)a.z; v[3] = (_Float16)a.w;
    v[4] = (_Float16)b.x; v[5] = (_Float16)b.y; v[6] = (_Float16)b.z; v[7] = (_Float16)b.w;
    return v;
}

union hu { _Float16 h; unsigned short u; };

// Persistent LSTM. 256 WGs = 16 batch groups (16 rows) x 16 column groups (32 H-cols
// = 128 gate cols). W frags in registers/AGPRs (f16). Cross-WG h exchange is done
// ENTIRELY with sc0+sc1 (LLC-coherent) memory ops + relaxed atomics: no acquire/release
// fences -> no bulk per-XCD L2 invalidate/writeback per step (that was the 14 us/step
// floor of rounds 2-3). Transposed GEMM: each lane's 4 acc regs are gates (i,f,g,o)
// of one (row, H-col) -> lane-local cell update.
__global__ __launch_bounds__(256, 1)
void lstm_persistent(const float* __restrict__ x0, const float* __restrict__ x1,
                     const float* __restrict__ wih, const float* __restrict__ whh,
                     const float* __restrict__ bih, const float* __restrict__ bhh,
                     _Float16* __restrict__ hb, int* __restrict__ cnt,
                     float* __restrict__ out) {
    __shared__ _Float16 Ab[16 * KP];

    const int tid  = threadIdx.x;
    const int lane = tid & 63;
    const int w    = tid >> 6;       // wave 0..3
    const int quad = lane >> 4;
    const int l16  = lane & 15;
    const int igrp = blockIdx.x & 15;    // batch group (16 rows)
    const int jcg  = blockIdx.x >> 4;    // column group (32 H-cols)
    const int mtb  = w * 2;              // my 2 M-tiles (of 8)

    // ---- W A-frags: global fp32 -> f16 regs/AGPRs, once ----
    // tile row m: gate q=m&3, H-col-in-tile ccl=m>>2; gc = q*512 + jcg*32 + mt*4 + ccl
    // A-frag layout: A[m=l16][k=quad*8+j], k-chunk kk*32
    const int q0  = l16 & 3, ccl = l16 >> 2;
    const int gc0 = q0 * HDIM + jcg * 32 + mtb * 4 + ccl;
    const int gc1 = gc0 + 4;
    half8 wf0[24], wf1[24];
#pragma unroll
    for (int kk = 0; kk < 24; ++kk) {
        int k0 = kk * 32 + quad * 8;
        const float* sA = (k0 < IDIM) ? wih + (size_t)gc0 * IDIM + k0
                                      : whh + (size_t)gc0 * HDIM + (k0 - IDIM);
        const float* sB = (k0 < IDIM) ? wih + (size_t)gc1 * IDIM + k0
                                      : whh + (size_t)gc1 * HDIM + (k0 - IDIM);
        wf0[kk] = cvt8(*(const float4*)sA, *(const float4*)(sA + 4));
        wf1[kk] = cvt8(*(const float4*)sB, *(const float4*)(sB + 4));
    }

    // ---- bias: C-frag row m = quad*4 + reg -> reg q = gate q at H-col (mt*4+quad) ----
    float bias0[4], bias1[4];
#pragma unroll
    for (int q = 0; q < 4; ++q) {
        int g0 = q * HDIM + jcg * 32 + mtb * 4 + quad;
        bias0[q] = bih[g0] + bhh[g0];
        bias1[q] = bih[g0 + 4] + bhh[g0 + 4];
    }

    const float* xp  = (igrp < 8) ? x0 : x1;
    const int   brow = (igrp & 7) * 16;
    const int   r0   = tid >> 5;            // my x rows r0, r0+8
    const int   o0   = (tid & 31) * 8;      // my x col chunk
    const int   grow = igrp * 16 + l16;     // my batch row (global)
    const int   cc0  = jcg * 32 + mtb * 4 + quad;  // my H-cols
    const int   cc1  = cc0 + 4;

    float c0 = 0.f, c1 = 0.f;
    int gaveup = 0;   // spin-timeout failsafe (lane 0 of each wave only)

#pragma unroll 1
    for (int t = 0; t < NSTEP; ++t) {
        // ---- prefetch x_t into regs (normal cached loads; overlaps the spin) ----
        const float* xr0 = xp + ((size_t)(brow + r0) * SLEN + t) * IDIM + o0;
        const float* xr1 = xr0 + (size_t)8 * SLEN * IDIM;
        float4 pa = *(const float4*)xr0, pb = *(const float4*)(xr0 + 4);
        float4 pc = *(const float4*)xr1, pd = *(const float4*)(xr1 + 4);

        // ---- wait: all 16 WGs of this group signalled step t-1 (relaxed LLC poll) ----
        if (t > 0) {
            if (lane == 0 && !gaveup) {
                const int* pcnt = &cnt[igrp * NSTEP + (t - 1)];
                int it = 0;
                while (__hip_atomic_load(pcnt, __ATOMIC_RELAXED, __HIP_MEMORY_SCOPE_AGENT) < GWG) {
                    __builtin_amdgcn_s_sleep(2);
                    if (++it > (1 << 20)) { gaveup = 1; break; }
                }
            }
            // compiler barrier only (workgroup scope: no L2 maintenance)
            __builtin_amdgcn_fence(__ATOMIC_ACQUIRE, "workgroup");
        }

        // ---- stage x_t (fp32->f16, normal path) ----
        *(half8*)&Ab[r0 * KP + o0]       = cvt8(pa, pb);
        *(half8*)&Ab[(r0 + 8) * KP + o0] = cvt8(pc, pd);

        // ---- stage h_{t-1}: 16 KB via sc0+sc1 loads (LLC-coherent, no fence) ----
        {
            const unsigned long long* hs8 = (const unsigned long long*)
                (hb + (size_t)((t + 1) & 1) * (NROW * HDIM) + (size_t)(igrp * 16) * HDIM);
#pragma unroll
            for (int p = 0; p < 8; ++p) {
                int c = tid + p * 256;    // consecutive lanes -> consecutive 8B chunks
                unsigned long long v =
                    __hip_atomic_load(hs8 + c, __ATOMIC_RELAXED, __HIP_MEMORY_SCOPE_AGENT);
                *(unsigned long long*)&Ab[(c >> 7) * KP + IDIM + (c & 127) * 4] = v;
            }
        }
        __syncthreads();   // barrier A: Ab fully staged

        // ---- GEMM: D[m=gatecol][n=row] += W[m][k] * Act[n][k] ----
        f32x4 acc0 = {bias0[0], bias0[1], bias0[2], bias0[3]};
        f32x4 acc1 = {bias1[0], bias1[1], bias1[2], bias1[3]};
        const _Float16* ab = &Ab[l16 * KP + quad * 8];
#pragma unroll
        for (int kk = 0; kk < 24; ++kk) {
            half8 bf = *(const half8*)(ab + kk * 32);
            acc0 = __builtin_amdgcn_mfma_f32_16x16x32_f16(wf0[kk], bf, acc0, 0, 0, 0);
            acc1 = __builtin_amdgcn_mfma_f32_16x16x32_f16(wf1[kk], bf, acc1, 0, 0, 0);
        }

        // ---- cell update (regs 0..3 = i,f,g,o), fp32 ----
        float i0 = sigm(acc0[0]), f0 = sigm(acc0[1]), g0 = tanh_f(acc0[2]), o0g = sigm(acc0[3]);
        c0 = f0 * c0 + i0 * g0;
        float h0 = o0g * tanh_f(c0);
        float i1 = sigm(acc1[0]), f1 = sigm(acc1[1]), g1 = tanh_f(acc1[2]), o1g = sigm(acc1[3]);
        c1 = f1 * c1 + i1 * g1;
        float h1 = o1g * tanh_f(c1);

        if (t < NSTEP - 1) {
            // h stores write-through to LLC (sc0 sc1); asm ends with vmcnt(0) drain
            // because the compiler cannot track asm-issued stores for the barrier.
            _Float16* hd = hb + (size_t)(t & 1) * (NROW * HDIM) + (size_t)grow * HDIM;
            hu u0; u0.h = (_Float16)h0;
            hu u1; u1.h = (_Float16)h1;
            unsigned int v0 = u0.u, v1 = u1.u;
            asm volatile(
                "global_store_short %0, %2, off sc0 sc1\n\t"
                "global_store_short %1, %3, off sc0 sc1\n\t"
                "s_waitcnt vmcnt(0)"
                :: "v"(hd + cc0), "v"(hd + cc1), "v"(v0), "v"(v1)
                : "memory");
            __syncthreads();   // barrier B: all h stores drained, Ab reads done
            if (tid == 0) {
                // relaxed RMW at LLC; ordered after drained h stores by program order
                __hip_atomic_fetch_add(&cnt[igrp * NSTEP + t], 1,
                                       __ATOMIC_RELAXED, __HIP_MEMORY_SCOPE_AGENT);
            }
        } else {
            out[(size_t)grow * HDIM + cc0] = h0;
            out[(size_t)grow * HDIM + cc1] = h1;
        }
    }
}

extern "C" void kernel_launch(void* const* d_in, const int* in_sizes, int n_in,
                              void* d_out, int out_size, void* d_ws, size_t ws_size,
                              hipStream_t stream) {
    const float* x0  = (const float*)d_in[0];   // [128,512,256] fp32
    const float* x1  = (const float*)d_in[1];
    const float* wih = (const float*)d_in[2];   // [2048,256]
    const float* whh = (const float*)d_in[3];   // [2048,512]
    const float* bih = (const float*)d_in[4];   // [2048]
    const float* bhh = (const float*)d_in[5];   // [2048]

    // ws: h ping-pong (2 x 256 KB f16) + per-(group,step) arrival counters
    _Float16* hb = (_Float16*)d_ws;
    int* cnt = (int*)((char*)d_ws + (size_t)2 * NROW * HDIM * sizeof(_Float16));
    size_t zbytes = (size_t)2 * NROW * HDIM * sizeof(_Float16)
                  + (size_t)NGRP * NSTEP * sizeof(int);
    hipMemsetAsync(d_ws, 0, zbytes, stream);   // zero h_{-1} + counters (ws is 0xAA-poisoned)

    lstm_persistent<<<dim3(256), dim3(256), 0, stream>>>(
        x0, x1, wih, whh, bih, bhh, hb, cnt, (float*)d_out);
}